// Round 15
// baseline (252.589 us; speedup 1.0000x reference)
//
#include <hip/hip_runtime.h>

// ---------------------------------------------------------------------------
// EntropyPrunedSelfAttention  (B=4, N=1024, C=768, H=12, hd=64)
// Round 15: (a) ks_fused BK=128 stages — Ks[2][128x72] (45.4KB total, still
// 3 blocks/CU), 4-uint4 prefetch, barriers 34->18, 2x compute per barrier.
// (b) k_mask folded into ks_fused via last-block doneCnt pattern (one fewer
// launch). kg_qkv/k_av/kg_proj unchanged from r14.
//
// Workspace (byte offsets):
//   xb      bf16[4096*768]      @ 0
//   qwb     bf16[2304*768]      @ 6291456
//   pwb     bf16[768*768]       @ 9830400
//   qb      bf16[48*1024*64]    @ 11010048
//   kb      bf16[48*1024*64]    @ 17301504
//   v       f32 [48*1024*64]    @ 23592960
//   ctxb    bf16[4096*768]      @ 36175872
//   lse     f32 [48*1024]       @ 42467328
//   mask    f32 [1024]          @ 42663936
//   keep    int [1]             @ 42668032
//   colSP   f32 [2048]          @ 42668544   (colS[1024] ++ colP[1024])
//   doneCnt int [1]             @ 42676736
// total ~42.7 MB
// ---------------------------------------------------------------------------

typedef __bf16 bf16x8 __attribute__((ext_vector_type(8)));
typedef __bf16 bf16x4 __attribute__((ext_vector_type(4)));
typedef float  f32x4  __attribute__((ext_vector_type(4)));

#define MFMA16(a, b, c) __builtin_amdgcn_mfma_f32_16x16x32_bf16((a), (b), (c), 0, 0, 0)
#define LOG2E_8 0.18033688f  /* 0.125 * log2(e) */

// --- 1. fp32 -> bf16 conversion + zero colSP/keepCnt/doneCnt ---------------
__global__ __launch_bounds__(256) void kc_conv(
    const float* __restrict__ x, const float* __restrict__ qw, const float* __restrict__ pw,
    __bf16* __restrict__ xb, __bf16* __restrict__ qwb, __bf16* __restrict__ pwb,
    float* __restrict__ colSP, int* __restrict__ keepCnt, int* __restrict__ doneCnt)
{
  const int i = blockIdx.x * 256 + threadIdx.x;
  const float4* src;
  __bf16* dst;
  int j;
  if (i < 786432)       { src = (const float4*)x;  dst = xb;  j = i; }
  else if (i < 1228800) { src = (const float4*)qw; dst = qwb; j = i - 786432; }
  else                  { src = (const float4*)pw; dst = pwb; j = i - 1228800; }
  const float4 f = src[j];
  bf16x4 o;
  o[0] = (__bf16)f.x; o[1] = (__bf16)f.y; o[2] = (__bf16)f.z; o[3] = (__bf16)f.w;
  *(bf16x4*)(dst + 4 * (size_t)j) = o;
  if (i < 2048) colSP[i] = 0.f;
  if (i == 0) { *keepCnt = 0; *doneCnt = 0; }
}

// --- 2. QKV GEMM (r14): 64x64 tiles, single-barrier double-buffered stages -
__global__ __launch_bounds__(256) void kg_qkv(
    const __bf16* __restrict__ A, const __bf16* __restrict__ Bm,
    __bf16* __restrict__ qb, __bf16* __restrict__ kb, float* __restrict__ v)
{
  __shared__ __bf16 As[2][64 * 72];
  __shared__ __bf16 Bs[2][64 * 72];
  const int tid = threadIdx.x;
  const int w = tid >> 6, lane = tid & 63, quad = lane >> 4, l = lane & 15;
  const int r0 = blockIdx.y * 64, c0 = blockIdx.x * 64;
  const int row = tid >> 3, ko = (tid & 7) * 8;
  const f32x4 zero = {0.f, 0.f, 0.f, 0.f};
  f32x4 acc[4];
#pragma unroll
  for (int ct = 0; ct < 4; ++ct) acc[ct] = zero;

  uint4 a0 = *(const uint4*)(A + (size_t)(r0 + row) * 768 + ko);
  uint4 a1 = *(const uint4*)(A + (size_t)(r0 + row + 32) * 768 + ko);
  uint4 b0 = *(const uint4*)(Bm + (size_t)(c0 + row) * 768 + ko);
  uint4 b1 = *(const uint4*)(Bm + (size_t)(c0 + row + 32) * 768 + ko);

  for (int k0 = 0; k0 < 768; k0 += 64) {
    const int buf = (k0 >> 6) & 1;
    *(uint4*)&As[buf][row * 72 + ko] = a0;
    *(uint4*)&As[buf][(row + 32) * 72 + ko] = a1;
    *(uint4*)&Bs[buf][row * 72 + ko] = b0;
    *(uint4*)&Bs[buf][(row + 32) * 72 + ko] = b1;
    __syncthreads();  // stage s visible; stage s+1 loads not yet issued
    if (k0 < 704) {
      a0 = *(const uint4*)(A + (size_t)(r0 + row) * 768 + k0 + 64 + ko);
      a1 = *(const uint4*)(A + (size_t)(r0 + row + 32) * 768 + k0 + 64 + ko);
      b0 = *(const uint4*)(Bm + (size_t)(c0 + row) * 768 + k0 + 64 + ko);
      b1 = *(const uint4*)(Bm + (size_t)(c0 + row + 32) * 768 + k0 + 64 + ko);
    }
    const bf16x8 af0 = *(const bf16x8*)&As[buf][(w * 16 + l) * 72 + quad * 8];
    const bf16x8 af1 = *(const bf16x8*)&As[buf][(w * 16 + l) * 72 + 32 + quad * 8];
#pragma unroll
    for (int ct = 0; ct < 4; ++ct) {
      const bf16x8 bf0 = *(const bf16x8*)&Bs[buf][(ct * 16 + l) * 72 + quad * 8];
      const bf16x8 bf1 = *(const bf16x8*)&Bs[buf][(ct * 16 + l) * 72 + 32 + quad * 8];
      acc[ct] = MFMA16(af0, bf0, acc[ct]);
      acc[ct] = MFMA16(af1, bf1, acc[ct]);
    }
  }
  const int part = c0 / 768;
  const int h = (c0 % 768) >> 6;
#pragma unroll
  for (int ct = 0; ct < 4; ++ct) {
    const int d = ct * 16 + l;
#pragma unroll
    for (int i = 0; i < 4; ++i) {
      const int rg = r0 + w * 16 + quad * 4 + i;
      const int b_ = rg >> 10, n = rg & 1023;
      const size_t off = ((size_t)(b_ * 12 + h) * 1024 + n) * 64 + d;
      const float val = acc[ct][i];
      if (part == 0)      qb[off] = (__bf16)val;
      else if (part == 1) kb[off] = (__bf16)val;
      else                v[off]  = val;
    }
  }
}

// --- 3. fused stats v5: BK=128 stages + folded mask ------------------------
// grid (48, 16): block = (bh, 64 rows) x 1024 cols. Wave w owns column-tile
// w within each 64-col half; 4 Q row-tiles resident. Ks[2][128x72] double-
// buffered, one barrier per stage (8 stages/pass). Last block computes mask.
__global__ __launch_bounds__(256) void ks_fused(
    const __bf16* __restrict__ qb, const __bf16* __restrict__ kb,
    float* __restrict__ lse, float* __restrict__ colSP,
    const int* __restrict__ cur_epoch, float* __restrict__ mask,
    int* __restrict__ keepCnt, int* __restrict__ doneCnt)
{
  __shared__ __bf16 Ks[2][128 * 72];
  __shared__ float sS[1024];
  __shared__ float sP[1024];
  __shared__ float zrow[64];
  __shared__ int lastFlag;
  const int tid = threadIdx.x;
  const int w = tid >> 6, lane = tid & 63, quad = lane >> 4, l = lane & 15;
  const int bh = blockIdx.x, r0 = blockIdx.y * 64;
  const int row = tid >> 3, ko = (tid & 7) * 8;
  for (int i = tid; i < 1024; i += 256) { sS[i] = 0.f; sP[i] = 0.f; }
  if (tid < 64) zrow[tid] = 0.f;

  const __bf16* qbase = qb + ((size_t)bh * 1024 + r0 + l) * 64;
  bf16x8 aq0[4], aq1[4];
#pragma unroll
  for (int rt = 0; rt < 4; ++rt) {
    aq0[rt] = *(const bf16x8*)(qbase + rt * 1024 + quad * 8);
    aq1[rt] = *(const bf16x8*)(qbase + rt * 1024 + 32 + quad * 8);
  }
  const __bf16* kbase = kb + (size_t)bh * 65536;  // [1024][64]
  const f32x4 zero = {0.f, 0.f, 0.f, 0.f};

  // prefetch chunk 0 (128 K-rows; 4 x uint4 per thread)
  uint4 ka[4];
#pragma unroll
  for (int t = 0; t < 4; ++t)
    ka[t] = *(const uint4*)(kbase + (size_t)(t * 32 + row) * 64 + ko);

  float z[16] = {};
  // ---- pass 1: row sums of exp (8 stages x 128 cols) ----
  for (int s = 0; s < 8; ++s) {
    __bf16* Kw = Ks[s & 1];
#pragma unroll
    for (int t = 0; t < 4; ++t)
      *(uint4*)&Kw[(t * 32 + row) * 72 + ko] = ka[t];
    __syncthreads();  // chunk s visible; no vmem in flight here
    const int nxt = (s + 1) & 7;  // s==7 prefetches chunk 0 for pass 2
#pragma unroll
    for (int t = 0; t < 4; ++t)
      ka[t] = *(const uint4*)(kbase + (size_t)(nxt * 128 + t * 32 + row) * 64 + ko);
#pragma unroll
    for (int half = 0; half < 2; ++half) {
      const int koff = (half * 64 + w * 16 + l) * 72 + quad * 8;
      const bf16x8 kf0 = *(const bf16x8*)&Kw[koff];
      const bf16x8 kf1 = *(const bf16x8*)&Kw[koff + 32];
#pragma unroll
      for (int rt = 0; rt < 4; ++rt) {
        f32x4 acc = MFMA16(aq0[rt], kf0, zero);
        acc = MFMA16(aq1[rt], kf1, acc);
#pragma unroll
        for (int r = 0; r < 4; ++r) z[rt * 4 + r] += exp2f(acc[r] * LOG2E_8);
      }
    }
  }
#pragma unroll
  for (int off = 1; off < 16; off <<= 1) {
#pragma unroll
    for (int i = 0; i < 16; ++i) z[i] += __shfl_xor(z[i], off);
  }
  if (l == 0) {
#pragma unroll
    for (int rt = 0; rt < 4; ++rt)
#pragma unroll
      for (int r = 0; r < 4; ++r)
        atomicAdd(&zrow[rt * 16 + quad * 4 + r], z[rt * 4 + r]);
  }
  __syncthreads();  // zrow complete
  if (tid < 64) lse[bh * 1024 + r0 + tid] = __logf(zrow[tid]);
  float nlb[16], nlg[16];  // -log2(Z), -ln(Z)
#pragma unroll
  for (int rt = 0; rt < 4; ++rt) {
#pragma unroll
    for (int r = 0; r < 4; ++r) {
      const float Z = zrow[rt * 16 + quad * 4 + r];
      const float lg = __logf(Z);
      nlg[rt * 4 + r] = -lg;
      nlb[rt * 4 + r] = -lg * 1.44269504f;
    }
  }

  // ---- pass 2: column sums of p and p*logp ----
  for (int s = 0; s < 8; ++s) {
    __bf16* Kw = Ks[s & 1];
#pragma unroll
    for (int t = 0; t < 4; ++t)
      *(uint4*)&Kw[(t * 32 + row) * 72 + ko] = ka[t];
    __syncthreads();
    if (s < 7) {
#pragma unroll
      for (int t = 0; t < 4; ++t)
        ka[t] = *(const uint4*)(kbase + (size_t)((s + 1) * 128 + t * 32 + row) * 64 + ko);
    }
#pragma unroll
    for (int half = 0; half < 2; ++half) {
      const int koff = (half * 64 + w * 16 + l) * 72 + quad * 8;
      const bf16x8 kf0 = *(const bf16x8*)&Kw[koff];
      const bf16x8 kf1 = *(const bf16x8*)&Kw[koff + 32];
      float cs = 0.f, cp = 0.f;
#pragma unroll
      for (int rt = 0; rt < 4; ++rt) {
        f32x4 acc = MFMA16(aq0[rt], kf0, zero);
        acc = MFMA16(aq1[rt], kf1, acc);
#pragma unroll
        for (int r = 0; r < 4; ++r) {
          const float a = acc[r];
          const float t = exp2f(fmaf(a, LOG2E_8, nlb[rt * 4 + r]));
          const float d = fmaf(a, 0.125f, nlg[rt * 4 + r]);
          cs += t;
          cp = fmaf(t, d, cp);
        }
      }
      cs += __shfl_xor(cs, 16); cs += __shfl_xor(cs, 32);
      cp += __shfl_xor(cp, 16); cp += __shfl_xor(cp, 32);
      if (lane < 16) {  // wave-private columns: plain LDS accumulate
        sS[s * 128 + half * 64 + w * 16 + l] += cs;
        sP[s * 128 + half * 64 + w * 16 + l] += cp;
      }
    }
  }
  __syncthreads();
  for (int i = tid; i < 1024; i += 256) {
    atomicAdd(&colSP[i], sS[i]);
    atomicAdd(&colSP[1024 + i], sP[i]);
  }

  // ---- folded mask: last block to finish computes mask + keepCnt ----
  __threadfence();
  if (tid == 0) {
    const int old = atomicAdd(doneCnt, 1);
    lastFlag = (old == 48 * 16 - 1);
  }
  __syncthreads();
  if (lastFlag) {
    __threadfence();
    const int ce = cur_epoch[0];
    float factor = 0.f;
    for (int i = 1; i <= ce; ++i) factor += __expf(-(float)i);
    const float thr = __logf(768.0f) - 5.0f * factor;
    int kcnt = 0;
    for (int jj = tid; jj < 1024; jj += 256) {
      const float sv = atomicAdd(&colSP[jj], 0.0f);        // coherent read
      const float pv = atomicAdd(&colSP[1024 + jj], 0.0f); // coherent read
      const float ent = __logf(sv) - pv / sv;
      const int kp = (ent <= thr) ? 1 : 0;
      mask[jj] = kp ? 1.0f : 0.0f;
      kcnt += kp;
    }
#pragma unroll
    for (int off = 1; off < 64; off <<= 1) kcnt += __shfl_xor(kcnt, off);
    if ((tid & 63) == 0 && kcnt) atomicAdd(keepCnt, kcnt);
  }
}

// --- 5. masked AV -> ctxb (bf16). No-op when no column survives. -----------
__global__ __launch_bounds__(256) void k_av(
    const __bf16* __restrict__ qb, const __bf16* __restrict__ kb,
    const float* __restrict__ v, const float* __restrict__ lse,
    const float* __restrict__ mask, const int* __restrict__ keepCnt,
    __bf16* __restrict__ ctxb)
{
  if (*keepCnt == 0) return;  // ctxb unused downstream in this case
  const int tid = threadIdx.x;
  const int bh = blockIdx.x, r0 = blockIdx.y * 32;
  const int b_ = bh / 12, h = bh % 12;
  __shared__ float qs[32][64];
  __shared__ float pbuf[4][8][64];
  for (int i = tid; i < 2048; i += 256)
    qs[i >> 6][i & 63] = (float)qb[((size_t)bh * 1024 + r0) * 64 + i];
  __syncthreads();
  const int w = tid >> 6, l = tid & 63, rb = w * 8;
  float ls[8];
#pragma unroll
  for (int i = 0; i < 8; ++i) ls[i] = lse[bh * 1024 + r0 + rb + i];
  float acc[8] = {};
  for (int chunk = 0; chunk < 16; ++chunk) {
    const float mk = mask[chunk * 64 + l];
    if (__ballot(mk != 0.0f) == 0ull) continue;  // block-uniform
    const __bf16* kp = kb + ((size_t)bh * 1024 + chunk * 64 + l) * 64;
    float s[8] = {};
    for (int d0 = 0; d0 < 64; d0 += 8) {
      const bf16x8 kf = *(const bf16x8*)(kp + d0);
#pragma unroll
      for (int dd = 0; dd < 8; ++dd) {
        const float kv = (float)kf[dd];
#pragma unroll
        for (int i = 0; i < 8; ++i) s[i] += qs[rb + i][d0 + dd] * kv;
      }
    }
    __syncthreads();
#pragma unroll
    for (int i = 0; i < 8; ++i)
      pbuf[w][i][l] = __expf(s[i] * 0.125f - ls[i]) * mk;
    __syncthreads();
    const float* vp = v + ((size_t)bh * 1024 + chunk * 64) * 64 + l;
    for (int jj = 0; jj < 64; ++jj) {
      const float vv = vp[(size_t)jj * 64];
#pragma unroll
      for (int i = 0; i < 8; ++i) acc[i] += pbuf[w][i][jj] * vv;
    }
  }
#pragma unroll
  for (int i = 0; i < 8; ++i)
    ctxb[((size_t)(b_ * 1024 + r0 + rb + i)) * 768 + h * 64 + l] = (__bf16)acc[i];
}

// --- 6. proj GEMM: out = ctxb @ pwb.T + bias; bias-only when keep==0 -------
__global__ __launch_bounds__(256) void kg_proj(
    const __bf16* __restrict__ A, const __bf16* __restrict__ Bm,
    const float* __restrict__ bias, const int* __restrict__ keepCnt,
    float* __restrict__ out)
{
  const int tid = threadIdx.x;
  const int w = tid >> 6, lane = tid & 63, quad = lane >> 4, l = lane & 15;
  const int r0 = blockIdx.y * 64, c0 = blockIdx.x * 64;
  if (*keepCnt == 0) {  // ctx == 0 -> out = bias (uniform branch)
#pragma unroll
    for (int ct = 0; ct < 4; ++ct) {
      const int c = c0 + ct * 16 + l;
      const float bv = bias[c];
#pragma unroll
      for (int i = 0; i < 4; ++i) {
        const int rg = r0 + w * 16 + quad * 4 + i;
        out[(size_t)rg * 768 + c] = bv;
      }
    }
    return;
  }
  __shared__ __bf16 As[64 * 72];
  __shared__ __bf16 Bs[64 * 72];
  const int row = tid >> 3, ko = (tid & 7) * 8;
  const f32x4 zero = {0.f, 0.f, 0.f, 0.f};
  f32x4 acc[4];
#pragma unroll
  for (int ct = 0; ct < 4; ++ct) acc[ct] = zero;

  uint4 a0 = *(const uint4*)(A + (size_t)(r0 + row) * 768 + ko);
  uint4 a1 = *(const uint4*)(A + (size_t)(r0 + row + 32) * 768 + ko);
  uint4 b0 = *(const uint4*)(Bm + (size_t)(c0 + row) * 768 + ko);
  uint4 b1 = *(const uint4*)(Bm + (size_t)(c0 + row + 32) * 768 + ko);

  for (int k0 = 0; k0 < 768; k0 += 64) {
    __syncthreads();
    *(uint4*)&As[row * 72 + ko] = a0;
    *(uint4*)&As[(row + 32) * 72 + ko] = a1;
    *(uint4*)&Bs[row * 72 + ko] = b0;
    *(uint4*)&Bs[(row + 32) * 72 + ko] = b1;
    __syncthreads();
    if (k0 < 704) {
      a0 = *(const uint4*)(A + (size_t)(r0 + row) * 768 + k0 + 64 + ko);
      a1 = *(const uint4*)(A + (size_t)(r0 + row + 32) * 768 + k0 + 64 + ko);
      b0 = *(const uint4*)(Bm + (size_t)(c0 + row) * 768 + k0 + 64 + ko);
      b1 = *(const uint4*)(Bm + (size_t)(c0 + row + 32) * 768 + k0 + 64 + ko);
    }
    const bf16x8 af0 = *(const bf16x8*)&As[(w * 16 + l) * 72 + quad * 8];
    const bf16x8 af1 = *(const bf16x8*)&As[(w * 16 + l) * 72 + 32 + quad * 8];
#pragma unroll
    for (int ct = 0; ct < 4; ++ct) {
      const bf16x8 bf0 = *(const bf16x8*)&Bs[(ct * 16 + l) * 72 + quad * 8];
      const bf16x8 bf1 = *(const bf16x8*)&Bs[(ct * 16 + l) * 72 + 32 + quad * 8];
      acc[ct] = MFMA16(af0, bf0, acc[ct]);
      acc[ct] = MFMA16(af1, bf1, acc[ct]);
    }
  }
#pragma unroll
  for (int ct = 0; ct < 4; ++ct) {
    const int c = c0 + ct * 16 + l;
#pragma unroll
    for (int i = 0; i < 4; ++i) {
      const int rg = r0 + w * 16 + quad * 4 + i;
      out[(size_t)rg * 768 + c] = acc[ct][i] + bias[c];
    }
  }
}

extern "C" void kernel_launch(void* const* d_in, const int* in_sizes, int n_in,
                              void* d_out, int out_size, void* d_ws, size_t ws_size,
                              hipStream_t stream)
{
  const float* x      = (const float*)d_in[0];
  const float* qkv_w  = (const float*)d_in[1];
  const float* proj_w = (const float*)d_in[2];
  const float* proj_b = (const float*)d_in[3];
  const int*   cur_ep = (const int*)d_in[4];

  char* W = (char*)d_ws;
  __bf16* xb    = (__bf16*)(W + 0);
  __bf16* qwb   = (__bf16*)(W + 6291456);
  __bf16* pwb   = (__bf16*)(W + 9830400);
  __bf16* qb    = (__bf16*)(W + 11010048);
  __bf16* kb    = (__bf16*)(W + 17301504);
  float*  v     = (float*) (W + 23592960);
  __bf16* ctxb  = (__bf16*)(W + 36175872);
  float*  lse   = (float*) (W + 42467328);
  float*  mask  = (float*) (W + 42663936);
  int*    keep  = (int*)   (W + 42668032);
  float*  colSP = (float*) (W + 42668544);
  int*    done  = (int*)   (W + 42676736);
  float*  out   = (float*)d_out;

  kc_conv<<<5376, 256, 0, stream>>>(x, qkv_w, proj_w, xb, qwb, pwb, colSP, keep, done);
  kg_qkv<<<dim3(36, 64), 256, 0, stream>>>(xb, qwb, qb, kb, v);
  ks_fused<<<dim3(48, 16), 256, 0, stream>>>(qb, kb, lse, colSP, cur_ep, mask, keep, done);
  k_av<<<dim3(48, 32), 256, 0, stream>>>(qb, kb, v, lse, mask, keep, ctxb);
  kg_proj<<<dim3(12, 64), 256, 0, stream>>>(ctxb, pwb, proj_b, keep, out);
}

// Round 16
// 252.255 us; speedup vs baseline: 1.0013x; 1.0013x over previous
//
#include <hip/hip_runtime.h>

// ---------------------------------------------------------------------------
// EntropyPrunedSelfAttention  (B=4, N=1024, C=768, H=12, hd=64)
// Round 16: stats column-split. r14's ks was grid-limited (768 blocks = 3/CU
// while LDS allowed 6). Block = 64 rows x 512 cols (grid 48x16x2 = 1536 = 
// 6/CU) with the IDENTICAL winning stage shape (4 resident Q-tiles, 8 MFMA
// per wave-stage, 2-uint4 prefetch, padded-72). Z crosses blocks -> pass1
// (rowZ atomics) + k_lsefin + pass2 (colstats, mask folded via doneCnt).
//
// Workspace (byte offsets):
//   xb      bf16[4096*768]      @ 0
//   qwb     bf16[2304*768]      @ 6291456
//   pwb     bf16[768*768]       @ 9830400
//   qb      bf16[48*1024*64]    @ 11010048
//   kb      bf16[48*1024*64]    @ 17301504
//   v       f32 [48*1024*64]    @ 23592960
//   ctxb    bf16[4096*768]      @ 36175872
//   lse     f32 [48*1024]       @ 42467328
//   mask    f32 [1024]          @ 42663936
//   keep    int [1]             @ 42668032
//   colSP   f32 [2048]          @ 42668544
//   doneCnt int [1]             @ 42676736
//   rowZ    f32 [48*1024]       @ 42676992
//   uw      f32 [2*48*1024]     @ 42873600   ((-lnZ, -log2Z) pairs)
// total ~43.3 MB
// ---------------------------------------------------------------------------

typedef __bf16 bf16x8 __attribute__((ext_vector_type(8)));
typedef __bf16 bf16x4 __attribute__((ext_vector_type(4)));
typedef float  f32x4  __attribute__((ext_vector_type(4)));

#define MFMA16(a, b, c) __builtin_amdgcn_mfma_f32_16x16x32_bf16((a), (b), (c), 0, 0, 0)
#define LOG2E_8 0.18033688f  /* 0.125 * log2(e) */

// --- 1. fp32 -> bf16 conversion + zero colSP/rowZ/keepCnt/doneCnt ----------
__global__ __launch_bounds__(256) void kc_conv(
    const float* __restrict__ x, const float* __restrict__ qw, const float* __restrict__ pw,
    __bf16* __restrict__ xb, __bf16* __restrict__ qwb, __bf16* __restrict__ pwb,
    float* __restrict__ colSP, float* __restrict__ rowZ,
    int* __restrict__ keepCnt, int* __restrict__ doneCnt)
{
  const int i = blockIdx.x * 256 + threadIdx.x;
  const float4* src;
  __bf16* dst;
  int j;
  if (i < 786432)       { src = (const float4*)x;  dst = xb;  j = i; }
  else if (i < 1228800) { src = (const float4*)qw; dst = qwb; j = i - 786432; }
  else                  { src = (const float4*)pw; dst = pwb; j = i - 1228800; }
  const float4 f = src[j];
  bf16x4 o;
  o[0] = (__bf16)f.x; o[1] = (__bf16)f.y; o[2] = (__bf16)f.z; o[3] = (__bf16)f.w;
  *(bf16x4*)(dst + 4 * (size_t)j) = o;
  if (i < 2048) colSP[i] = 0.f;
  if (i < 49152) rowZ[i] = 0.f;
  if (i == 0) { *keepCnt = 0; *doneCnt = 0; }
}

// --- 2. QKV GEMM (r14): 64x64 tiles, single-barrier double-buffered stages -
__global__ __launch_bounds__(256) void kg_qkv(
    const __bf16* __restrict__ A, const __bf16* __restrict__ Bm,
    __bf16* __restrict__ qb, __bf16* __restrict__ kb, float* __restrict__ v)
{
  __shared__ __bf16 As[2][64 * 72];
  __shared__ __bf16 Bs[2][64 * 72];
  const int tid = threadIdx.x;
  const int w = tid >> 6, lane = tid & 63, quad = lane >> 4, l = lane & 15;
  const int r0 = blockIdx.y * 64, c0 = blockIdx.x * 64;
  const int row = tid >> 3, ko = (tid & 7) * 8;
  const f32x4 zero = {0.f, 0.f, 0.f, 0.f};
  f32x4 acc[4];
#pragma unroll
  for (int ct = 0; ct < 4; ++ct) acc[ct] = zero;

  uint4 a0 = *(const uint4*)(A + (size_t)(r0 + row) * 768 + ko);
  uint4 a1 = *(const uint4*)(A + (size_t)(r0 + row + 32) * 768 + ko);
  uint4 b0 = *(const uint4*)(Bm + (size_t)(c0 + row) * 768 + ko);
  uint4 b1 = *(const uint4*)(Bm + (size_t)(c0 + row + 32) * 768 + ko);

  for (int k0 = 0; k0 < 768; k0 += 64) {
    const int buf = (k0 >> 6) & 1;
    *(uint4*)&As[buf][row * 72 + ko] = a0;
    *(uint4*)&As[buf][(row + 32) * 72 + ko] = a1;
    *(uint4*)&Bs[buf][row * 72 + ko] = b0;
    *(uint4*)&Bs[buf][(row + 32) * 72 + ko] = b1;
    __syncthreads();
    if (k0 < 704) {
      a0 = *(const uint4*)(A + (size_t)(r0 + row) * 768 + k0 + 64 + ko);
      a1 = *(const uint4*)(A + (size_t)(r0 + row + 32) * 768 + k0 + 64 + ko);
      b0 = *(const uint4*)(Bm + (size_t)(c0 + row) * 768 + k0 + 64 + ko);
      b1 = *(const uint4*)(Bm + (size_t)(c0 + row + 32) * 768 + k0 + 64 + ko);
    }
    const bf16x8 af0 = *(const bf16x8*)&As[buf][(w * 16 + l) * 72 + quad * 8];
    const bf16x8 af1 = *(const bf16x8*)&As[buf][(w * 16 + l) * 72 + 32 + quad * 8];
#pragma unroll
    for (int ct = 0; ct < 4; ++ct) {
      const bf16x8 bf0 = *(const bf16x8*)&Bs[buf][(ct * 16 + l) * 72 + quad * 8];
      const bf16x8 bf1 = *(const bf16x8*)&Bs[buf][(ct * 16 + l) * 72 + 32 + quad * 8];
      acc[ct] = MFMA16(af0, bf0, acc[ct]);
      acc[ct] = MFMA16(af1, bf1, acc[ct]);
    }
  }
  const int part = c0 / 768;
  const int h = (c0 % 768) >> 6;
#pragma unroll
  for (int ct = 0; ct < 4; ++ct) {
    const int d = ct * 16 + l;
#pragma unroll
    for (int i = 0; i < 4; ++i) {
      const int rg = r0 + w * 16 + quad * 4 + i;
      const int b_ = rg >> 10, n = rg & 1023;
      const size_t off = ((size_t)(b_ * 12 + h) * 1024 + n) * 64 + d;
      const float val = acc[ct][i];
      if (part == 0)      qb[off] = (__bf16)val;
      else if (part == 1) kb[off] = (__bf16)val;
      else                v[off]  = val;
    }
  }
}

// --- 3a. stats pass 1: rowZ partials. grid (48, 16, 2) ---------------------
// Block = 64 rows x 512 cols; wave w owns column-tile w of each 64-col chunk.
// Same stage shape as r11: 2-uint4 prefetch, padded-72, 1 barrier/stage.
__global__ __launch_bounds__(256) void ks_pass1(
    const __bf16* __restrict__ qb, const __bf16* __restrict__ kb,
    float* __restrict__ rowZ)
{
  __shared__ __bf16 Ks[2][64 * 72];
  const int tid = threadIdx.x;
  const int w = tid >> 6, lane = tid & 63, quad = lane >> 4, l = lane & 15;
  const int bh = blockIdx.x, r0 = blockIdx.y * 64, c0 = blockIdx.z * 512;
  const int row = tid >> 3, ko = (tid & 7) * 8;

  const __bf16* qbase = qb + ((size_t)bh * 1024 + r0 + l) * 64;
  bf16x8 aq0[4], aq1[4];
#pragma unroll
  for (int rt = 0; rt < 4; ++rt) {
    aq0[rt] = *(const bf16x8*)(qbase + rt * 1024 + quad * 8);
    aq1[rt] = *(const bf16x8*)(qbase + rt * 1024 + 32 + quad * 8);
  }
  const __bf16* kbase = kb + (size_t)bh * 65536 + (size_t)c0 * 64;
  const f32x4 zero = {0.f, 0.f, 0.f, 0.f};
  const int koff = (w * 16 + l) * 72 + quad * 8;

  uint4 ka0 = *(const uint4*)(kbase + (size_t)row * 64 + ko);
  uint4 ka1 = *(const uint4*)(kbase + (size_t)(row + 32) * 64 + ko);

  float z[16] = {};
  for (int s = 0; s < 8; ++s) {
    __bf16* Kw = Ks[s & 1];
    *(uint4*)&Kw[row * 72 + ko] = ka0;
    *(uint4*)&Kw[(row + 32) * 72 + ko] = ka1;
    __syncthreads();
    const int nxt = (s + 1) & 7;  // s==7: harmless dummy reload of chunk 0
    ka0 = *(const uint4*)(kbase + (size_t)(nxt * 64 + row) * 64 + ko);
    ka1 = *(const uint4*)(kbase + (size_t)(nxt * 64 + row + 32) * 64 + ko);
    const bf16x8 kf0 = *(const bf16x8*)&Kw[koff];
    const bf16x8 kf1 = *(const bf16x8*)&Kw[koff + 32];
#pragma unroll
    for (int rt = 0; rt < 4; ++rt) {
      f32x4 acc = MFMA16(aq0[rt], kf0, zero);
      acc = MFMA16(aq1[rt], kf1, acc);
#pragma unroll
      for (int r = 0; r < 4; ++r) z[rt * 4 + r] += exp2f(acc[r] * LOG2E_8);
    }
  }
#pragma unroll
  for (int off = 1; off < 16; off <<= 1) {
#pragma unroll
    for (int i = 0; i < 16; ++i) z[i] += __shfl_xor(z[i], off);
  }
  if (l == 0) {
#pragma unroll
    for (int rt = 0; rt < 4; ++rt)
#pragma unroll
      for (int r = 0; r < 4; ++r)
        atomicAdd(&rowZ[bh * 1024 + r0 + rt * 16 + quad * 4 + r], z[rt * 4 + r]);
  }
}

// --- 3b. finalize: lse = lnZ, uw = (-lnZ, -log2Z) --------------------------
__global__ void k_lsefin(const float* __restrict__ rowZ, float* __restrict__ lse,
                         float* __restrict__ uw)
{
  const int i = blockIdx.x * 256 + threadIdx.x;
  const float Z = rowZ[i];
  const float lg = __logf(Z);
  lse[i] = lg;
  float2 p; p.x = -lg; p.y = -lg * 1.44269504f;
  *(float2*)(uw + 2 * (size_t)i) = p;
}

// --- 3c. stats pass 2: column sums + folded mask. grid (48, 16, 2) ---------
__global__ __launch_bounds__(256) void ks_pass2(
    const __bf16* __restrict__ qb, const __bf16* __restrict__ kb,
    const float* __restrict__ uw, float* __restrict__ colSP,
    const int* __restrict__ cur_epoch, float* __restrict__ mask,
    int* __restrict__ keepCnt, int* __restrict__ doneCnt)
{
  __shared__ __bf16 Ks[2][64 * 72];
  __shared__ float sS[512];
  __shared__ float sP[512];
  __shared__ float2 uwS[64];
  __shared__ int lastFlag;
  const int tid = threadIdx.x;
  const int w = tid >> 6, lane = tid & 63, quad = lane >> 4, l = lane & 15;
  const int bh = blockIdx.x, r0 = blockIdx.y * 64, c0 = blockIdx.z * 512;
  const int row = tid >> 3, ko = (tid & 7) * 8;
  for (int i = tid; i < 512; i += 256) { sS[i] = 0.f; sP[i] = 0.f; }
  if (tid < 64) uwS[tid] = ((const float2*)uw)[bh * 1024 + r0 + tid];

  const __bf16* qbase = qb + ((size_t)bh * 1024 + r0 + l) * 64;
  bf16x8 aq0[4], aq1[4];
#pragma unroll
  for (int rt = 0; rt < 4; ++rt) {
    aq0[rt] = *(const bf16x8*)(qbase + rt * 1024 + quad * 8);
    aq1[rt] = *(const bf16x8*)(qbase + rt * 1024 + 32 + quad * 8);
  }
  const __bf16* kbase = kb + (size_t)bh * 65536 + (size_t)c0 * 64;
  const f32x4 zero = {0.f, 0.f, 0.f, 0.f};
  const int koff = (w * 16 + l) * 72 + quad * 8;

  uint4 ka0 = *(const uint4*)(kbase + (size_t)row * 64 + ko);
  uint4 ka1 = *(const uint4*)(kbase + (size_t)(row + 32) * 64 + ko);

  __syncthreads();  // sS/uwS init complete
  float nlg[16], nlb[16];
#pragma unroll
  for (int rt = 0; rt < 4; ++rt) {
#pragma unroll
    for (int r = 0; r < 4; ++r) {
      const float2 p = uwS[rt * 16 + quad * 4 + r];
      nlg[rt * 4 + r] = p.x;  // -lnZ
      nlb[rt * 4 + r] = p.y;  // -log2Z
    }
  }

  for (int s = 0; s < 8; ++s) {
    __bf16* Kw = Ks[s & 1];
    *(uint4*)&Kw[row * 72 + ko] = ka0;
    *(uint4*)&Kw[(row + 32) * 72 + ko] = ka1;
    __syncthreads();
    if (s < 7) {
      ka0 = *(const uint4*)(kbase + (size_t)((s + 1) * 64 + row) * 64 + ko);
      ka1 = *(const uint4*)(kbase + (size_t)((s + 1) * 64 + row + 32) * 64 + ko);
    }
    const bf16x8 kf0 = *(const bf16x8*)&Kw[koff];
    const bf16x8 kf1 = *(const bf16x8*)&Kw[koff + 32];
    float cs = 0.f, cp = 0.f;
#pragma unroll
    for (int rt = 0; rt < 4; ++rt) {
      f32x4 acc = MFMA16(aq0[rt], kf0, zero);
      acc = MFMA16(aq1[rt], kf1, acc);
#pragma unroll
      for (int r = 0; r < 4; ++r) {
        const float a = acc[r];
        const float t = exp2f(fmaf(a, LOG2E_8, nlb[rt * 4 + r]));  // p
        const float d = fmaf(a, 0.125f, nlg[rt * 4 + r]);          // logp
        cs += t;
        cp = fmaf(t, d, cp);
      }
    }
    cs += __shfl_xor(cs, 16); cs += __shfl_xor(cs, 32);
    cp += __shfl_xor(cp, 16); cp += __shfl_xor(cp, 32);
    if (lane < 16) {  // wave-private columns: plain LDS accumulate
      sS[s * 64 + w * 16 + l] += cs;
      sP[s * 64 + w * 16 + l] += cp;
    }
  }
  __syncthreads();
  for (int i = tid; i < 512; i += 256) {
    atomicAdd(&colSP[c0 + i], sS[i]);
    atomicAdd(&colSP[1024 + c0 + i], sP[i]);
  }

  // ---- folded mask: last block computes mask + keepCnt ----
  __threadfence();
  if (tid == 0) {
    const int old = atomicAdd(doneCnt, 1);
    lastFlag = (old == 48 * 16 * 2 - 1);
  }
  __syncthreads();
  if (lastFlag) {
    __threadfence();
    const int ce = cur_epoch[0];
    float factor = 0.f;
    for (int i = 1; i <= ce; ++i) factor += __expf(-(float)i);
    const float thr = __logf(768.0f) - 5.0f * factor;
    int kcnt = 0;
    for (int jj = tid; jj < 1024; jj += 256) {
      const float sv = atomicAdd(&colSP[jj], 0.0f);
      const float pv = atomicAdd(&colSP[1024 + jj], 0.0f);
      const float ent = __logf(sv) - pv / sv;
      const int kp = (ent <= thr) ? 1 : 0;
      mask[jj] = kp ? 1.0f : 0.0f;
      kcnt += kp;
    }
#pragma unroll
    for (int off = 1; off < 64; off <<= 1) kcnt += __shfl_xor(kcnt, off);
    if ((tid & 63) == 0 && kcnt) atomicAdd(keepCnt, kcnt);
  }
}

// --- 5. masked AV -> ctxb (bf16). No-op when no column survives. -----------
__global__ __launch_bounds__(256) void k_av(
    const __bf16* __restrict__ qb, const __bf16* __restrict__ kb,
    const float* __restrict__ v, const float* __restrict__ lse,
    const float* __restrict__ mask, const int* __restrict__ keepCnt,
    __bf16* __restrict__ ctxb)
{
  if (*keepCnt == 0) return;
  const int tid = threadIdx.x;
  const int bh = blockIdx.x, r0 = blockIdx.y * 32;
  const int b_ = bh / 12, h = bh % 12;
  __shared__ float qs[32][64];
  __shared__ float pbuf[4][8][64];
  for (int i = tid; i < 2048; i += 256)
    qs[i >> 6][i & 63] = (float)qb[((size_t)bh * 1024 + r0) * 64 + i];
  __syncthreads();
  const int w = tid >> 6, l = tid & 63, rb = w * 8;
  float ls[8];
#pragma unroll
  for (int i = 0; i < 8; ++i) ls[i] = lse[bh * 1024 + r0 + rb + i];
  float acc[8] = {};
  for (int chunk = 0; chunk < 16; ++chunk) {
    const float mk = mask[chunk * 64 + l];
    if (__ballot(mk != 0.0f) == 0ull) continue;
    const __bf16* kp = kb + ((size_t)bh * 1024 + chunk * 64 + l) * 64;
    float s[8] = {};
    for (int d0 = 0; d0 < 64; d0 += 8) {
      const bf16x8 kf = *(const bf16x8*)(kp + d0);
#pragma unroll
      for (int dd = 0; dd < 8; ++dd) {
        const float kv = (float)kf[dd];
#pragma unroll
        for (int i = 0; i < 8; ++i) s[i] += qs[rb + i][d0 + dd] * kv;
      }
    }
    __syncthreads();
#pragma unroll
    for (int i = 0; i < 8; ++i)
      pbuf[w][i][l] = __expf(s[i] * 0.125f - ls[i]) * mk;
    __syncthreads();
    const float* vp = v + ((size_t)bh * 1024 + chunk * 64) * 64 + l;
    for (int jj = 0; jj < 64; ++jj) {
      const float vv = vp[(size_t)jj * 64];
#pragma unroll
      for (int i = 0; i < 8; ++i) acc[i] += pbuf[w][i][jj] * vv;
    }
  }
#pragma unroll
  for (int i = 0; i < 8; ++i)
    ctxb[((size_t)(b_ * 1024 + r0 + rb + i)) * 768 + h * 64 + l] = (__bf16)acc[i];
}

// --- 6. proj GEMM: out = ctxb @ pwb.T + bias; bias-only when keep==0 -------
__global__ __launch_bounds__(256) void kg_proj(
    const __bf16* __restrict__ A, const __bf16* __restrict__ Bm,
    const float* __restrict__ bias, const int* __restrict__ keepCnt,
    float* __restrict__ out)
{
  const int tid = threadIdx.x;
  const int w = tid >> 6, lane = tid & 63, quad = lane >> 4, l = lane & 15;
  const int r0 = blockIdx.y * 64, c0 = blockIdx.x * 64;
  if (*keepCnt == 0) {
#pragma unroll
    for (int ct = 0; ct < 4; ++ct) {
      const int c = c0 + ct * 16 + l;
      const float bv = bias[c];
#pragma unroll
      for (int i = 0; i < 4; ++i) {
        const int rg = r0 + w * 16 + quad * 4 + i;
        out[(size_t)rg * 768 + c] = bv;
      }
    }
    return;
  }
  __shared__ __bf16 As[64 * 72];
  __shared__ __bf16 Bs[64 * 72];
  const int row = tid >> 3, ko = (tid & 7) * 8;
  const f32x4 zero = {0.f, 0.f, 0.f, 0.f};
  f32x4 acc[4];
#pragma unroll
  for (int ct = 0; ct < 4; ++ct) acc[ct] = zero;

  uint4 a0 = *(const uint4*)(A + (size_t)(r0 + row) * 768 + ko);
  uint4 a1 = *(const uint4*)(A + (size_t)(r0 + row + 32) * 768 + ko);
  uint4 b0 = *(const uint4*)(Bm + (size_t)(c0 + row) * 768 + ko);
  uint4 b1 = *(const uint4*)(Bm + (size_t)(c0 + row + 32) * 768 + ko);

  for (int k0 = 0; k0 < 768; k0 += 64) {
    __syncthreads();
    *(uint4*)&As[row * 72 + ko] = a0;
    *(uint4*)&As[(row + 32) * 72 + ko] = a1;
    *(uint4*)&Bs[row * 72 + ko] = b0;
    *(uint4*)&Bs[(row + 32) * 72 + ko] = b1;
    __syncthreads();
    if (k0 < 704) {
      a0 = *(const uint4*)(A + (size_t)(r0 + row) * 768 + k0 + 64 + ko);
      a1 = *(const uint4*)(A + (size_t)(r0 + row + 32) * 768 + k0 + 64 + ko);
      b0 = *(const uint4*)(Bm + (size_t)(c0 + row) * 768 + k0 + 64 + ko);
      b1 = *(const uint4*)(Bm + (size_t)(c0 + row + 32) * 768 + k0 + 64 + ko);
    }
    const bf16x8 af0 = *(const bf16x8*)&As[(w * 16 + l) * 72 + quad * 8];
    const bf16x8 af1 = *(const bf16x8*)&As[(w * 16 + l) * 72 + 32 + quad * 8];
#pragma unroll
    for (int ct = 0; ct < 4; ++ct) {
      const bf16x8 bf0 = *(const bf16x8*)&Bs[(ct * 16 + l) * 72 + quad * 8];
      const bf16x8 bf1 = *(const bf16x8*)&Bs[(ct * 16 + l) * 72 + 32 + quad * 8];
      acc[ct] = MFMA16(af0, bf0, acc[ct]);
      acc[ct] = MFMA16(af1, bf1, acc[ct]);
    }
  }
#pragma unroll
  for (int ct = 0; ct < 4; ++ct) {
    const int c = c0 + ct * 16 + l;
#pragma unroll
    for (int i = 0; i < 4; ++i) {
      const int rg = r0 + w * 16 + quad * 4 + i;
      out[(size_t)rg * 768 + c] = acc[ct][i] + bias[c];
    }
  }
}

extern "C" void kernel_launch(void* const* d_in, const int* in_sizes, int n_in,
                              void* d_out, int out_size, void* d_ws, size_t ws_size,
                              hipStream_t stream)
{
  const float* x      = (const float*)d_in[0];
  const float* qkv_w  = (const float*)d_in[1];
  const float* proj_w = (const float*)d_in[2];
  const float* proj_b = (const float*)d_in[3];
  const int*   cur_ep = (const int*)d_in[4];

  char* W = (char*)d_ws;
  __bf16* xb    = (__bf16*)(W + 0);
  __bf16* qwb   = (__bf16*)(W + 6291456);
  __bf16* pwb   = (__bf16*)(W + 9830400);
  __bf16* qb    = (__bf16*)(W + 11010048);
  __bf16* kb    = (__bf16*)(W + 17301504);
  float*  v     = (float*) (W + 23592960);
  __bf16* ctxb  = (__bf16*)(W + 36175872);
  float*  lse   = (float*) (W + 42467328);
  float*  mask  = (float*) (W + 42663936);
  int*    keep  = (int*)   (W + 42668032);
  float*  colSP = (float*) (W + 42668544);
  int*    done  = (int*)   (W + 42676736);
  float*  rowZ  = (float*) (W + 42676992);
  float*  uw    = (float*) (W + 42873600);
  float*  out   = (float*)d_out;

  kc_conv<<<5376, 256, 0, stream>>>(x, qkv_w, proj_w, xb, qwb, pwb, colSP, rowZ, keep, done);
  kg_qkv<<<dim3(36, 64), 256, 0, stream>>>(xb, qwb, qb, kb, v);
  ks_pass1<<<dim3(48, 16, 2), 256, 0, stream>>>(qb, kb, rowZ);
  k_lsefin<<<192, 256, 0, stream>>>(rowZ, lse, uw);
  ks_pass2<<<dim3(48, 16, 2), 256, 0, stream>>>(qb, kb, uw, colSP, cur_ep, mask, keep, done);
  k_av<<<dim3(48, 32), 256, 0, stream>>>(qb, kb, v, lse, mask, keep, ctxb);
  kg_proj<<<dim3(12, 64), 256, 0, stream>>>(ctxb, pwb, proj_b, keep, out);
}